// Round 3
// baseline (128.421 us; speedup 1.0000x reference)
//
#include <hip/hip_runtime.h>
#include <stdint.h>

#define N_PTS 256
#define BIG_F 66049.0f   // 257^2 sentinel from reference

typedef unsigned long long ull;

template<int CTRL>
__device__ __forceinline__ float dpp_min1(float x) {
    int xi = __float_as_int(x);
    int yi = __builtin_amdgcn_update_dpp(xi, xi, CTRL, 0xf, 0xf, false);
    return fminf(x, __int_as_float(yi));
}

// Two INDEPENDENT wave64 min-reductions, interleaved so each value's ops fill
// the other's DPP wait-state slots. Results returned uniform (readlane 63).
__device__ __forceinline__ void wave_min2(float& a, float& b) {
    a = dpp_min1<0x111>(a); b = dpp_min1<0x111>(b); // row_shr:1
    a = dpp_min1<0x112>(a); b = dpp_min1<0x112>(b); // row_shr:2
    a = dpp_min1<0x114>(a); b = dpp_min1<0x114>(b); // row_shr:4
    a = dpp_min1<0x118>(a); b = dpp_min1<0x118>(b); // row_shr:8
    a = dpp_min1<0x142>(a); b = dpp_min1<0x142>(b); // row_bcast:15
    a = dpp_min1<0x143>(a); b = dpp_min1<0x143>(b); // row_bcast:31
    a = __int_as_float(__builtin_amdgcn_readlane(__float_as_int(a), 63));
    b = __int_as_float(__builtin_amdgcn_readlane(__float_as_int(b), 63));
}

__device__ __forceinline__ float wave_min1(float a) {
    a = dpp_min1<0x111>(a);
    a = dpp_min1<0x112>(a);
    a = dpp_min1<0x114>(a);
    a = dpp_min1<0x118>(a);
    a = dpp_min1<0x142>(a);
    a = dpp_min1<0x143>(a);
    return __int_as_float(__builtin_amdgcn_readlane(__float_as_int(a), 63));
}

// exact first-min-wins: slot-major ballots, lowest set bit
__device__ __forceinline__ int pick_k(ull e0, ull e1, ull e2, ull e3) {
    return e0 ? (__ffsll((long long)e0) - 1)
         : e1 ? (64  + __ffsll((long long)e1) - 1)
         : e2 ? (128 + __ffsll((long long)e2) - 1)
         :      (192 + __ffsll((long long)e3) - 1);
}

__device__ __forceinline__ void poison(int k, int lane,
    float& px0, float& px1, float& px2, float& px3) {
    const float NANF = __int_as_float(0x7fc00000);
    const int  ks  = k >> 6;
    const bool hit = (lane == (k & 63));
    px0 = (hit && ks == 0) ? NANF : px0;
    px1 = (hit && ks == 1) ? NANF : px1;
    px2 = (hit && ks == 2) ? NANF : px2;
    px3 = (hit && ks == 3) ? NANF : px3;
}

// One 64-target phase, processed as 32 speculative PAIRS (j, j+1).
// A is exact; B's speculative argmin over the pre-A set is valid unless it
// equals kA (first-min-wins: masking kA only changes B's answer if B's first
// achiever IS kA). Rare collision -> wave-uniform redo over post-poison set.
__device__ __forceinline__ void greedy_phase_pair(
    float txc, float tyc, int lane, float& acc,
    float& px0, float& py0, float& px1, float& py1,
    float& px2, float& py2, float& px3, float& py3)
{
    #pragma clang fp contract(off)
    #pragma unroll 1
    for (int j2 = 0; j2 < 64; j2 += 2) {
        float tAx = __int_as_float(__builtin_amdgcn_readlane(__float_as_int(txc), j2));
        float tAy = __int_as_float(__builtin_amdgcn_readlane(__float_as_int(tyc), j2));
        float tBx = __int_as_float(__builtin_amdgcn_readlane(__float_as_int(txc), j2 + 1));
        float tBy = __int_as_float(__builtin_amdgcn_readlane(__float_as_int(tyc), j2 + 1));

        // distances for BOTH targets over the same used-set (contract OFF:
        // bit-exact vs fp32 numpy reference -> identical greedy trajectory)
        float ax0 = tAx - px0, ay0 = tAy - py0;
        float ax1 = tAx - px1, ay1 = tAy - py1;
        float ax2 = tAx - px2, ay2 = tAy - py2;
        float ax3 = tAx - px3, ay3 = tAy - py3;
        float dA0 = ax0 * ax0 + ay0 * ay0;
        float dA1 = ax1 * ax1 + ay1 * ay1;
        float dA2 = ax2 * ax2 + ay2 * ay2;
        float dA3 = ax3 * ax3 + ay3 * ay3;
        float bx0 = tBx - px0, by0 = tBy - py0;
        float bx1 = tBx - px1, by1 = tBy - py1;
        float bx2 = tBx - px2, by2 = tBy - py2;
        float bx3 = tBx - px3, by3 = tBy - py3;
        float dB0 = bx0 * bx0 + by0 * by0;
        float dB1 = bx1 * bx1 + by1 * by1;
        float dB2 = bx2 * bx2 + by2 * by2;
        float dB3 = bx3 * bx3 + by3 * by3;

        float mA = fminf(fminf(dA0, dA1), fminf(dA2, dA3));
        float mB = fminf(fminf(dB0, dB1), fminf(dB2, dB3));
        wave_min2(mA, mB);

        ull eA0 = __ballot(dA0 == mA);
        ull eA1 = __ballot(dA1 == mA);
        ull eA2 = __ballot(dA2 == mA);
        ull eA3 = __ballot(dA3 == mA);
        ull eB0 = __ballot(dB0 == mB);
        ull eB1 = __ballot(dB1 == mB);
        ull eB2 = __ballot(dB2 == mB);
        ull eB3 = __ballot(dB3 == mB);

        // resolve A exactly
        int kA = pick_k(eA0, eA1, eA2, eA3);
        bool okA = (mA < BIG_F);
        acc += okA ? mA : BIG_F;
        kA = okA ? kA : 0;
        poison(kA, lane, px0, px1, px2, px3);

        // resolve B speculatively; redo iff its pick was just consumed by A
        int kB = pick_k(eB0, eB1, eB2, eB3);
        if (kB == kA) {
            float rx0 = tBx - px0, ry0 = tBy - py0;
            float rx1 = tBx - px1, ry1 = tBy - py1;
            float rx2 = tBx - px2, ry2 = tBy - py2;
            float rx3 = tBx - px3, ry3 = tBy - py3;
            float r0 = rx0 * rx0 + ry0 * ry0;
            float r1 = rx1 * rx1 + ry1 * ry1;
            float r2 = rx2 * rx2 + ry2 * ry2;
            float r3 = rx3 * rx3 + ry3 * ry3;
            float m2 = fminf(fminf(r0, r1), fminf(r2, r3));
            m2 = wave_min1(m2);
            ull f0 = __ballot(r0 == m2);
            ull f1 = __ballot(r1 == m2);
            ull f2 = __ballot(r2 == m2);
            ull f3 = __ballot(r3 == m2);
            kB = pick_k(f0, f1, f2, f3);
            mB = m2;
        }
        bool okB = (mB < BIG_F);
        acc += okB ? mB : BIG_F;
        kB = okB ? kB : 0;
        poison(kB, lane, px0, px1, px2, px3);
    }
}

// One wave per batch. Lane L owns input candidates k = s*64 + L (s=0..3).
__global__ __launch_bounds__(256) void greedy_match_kernel(
    const float* __restrict__ input,
    const float* __restrict__ targets,
    float* __restrict__ out,
    int B, float scale)
{
    __shared__ float wsum[4];
    const int lane = threadIdx.x & 63;
    const int wid  = threadIdx.x >> 6;
    const int b    = blockIdx.x * 4 + wid;

    float acc = 0.0f;
    if (b < B) {
        const float2* pin = (const float2*)(input   + (size_t)b * (2 * N_PTS));
        const float2* ptg = (const float2*)(targets + (size_t)b * (2 * N_PTS));

        float2 p0 = pin[lane],       t0 = ptg[lane];
        float2 p1 = pin[64 + lane],  t1 = ptg[64 + lane];
        float2 p2 = pin[128 + lane], t2 = ptg[128 + lane];
        float2 p3 = pin[192 + lane], t3 = ptg[192 + lane];

        float px0 = p0.x, py0 = p0.y, px1 = p1.x, py1 = p1.y;
        float px2 = p2.x, py2 = p2.y, px3 = p3.x, py3 = p3.y;

        greedy_phase_pair(t0.x, t0.y, lane, acc, px0, py0, px1, py1, px2, py2, px3, py3);
        greedy_phase_pair(t1.x, t1.y, lane, acc, px0, py0, px1, py1, px2, py2, px3, py3);
        greedy_phase_pair(t2.x, t2.y, lane, acc, px0, py0, px1, py1, px2, py2, px3, py3);
        greedy_phase_pair(t3.x, t3.y, lane, acc, px0, py0, px1, py1, px2, py2, px3, py3);
    }

    if (lane == 0) wsum[wid] = acc;
    __syncthreads();
    if (threadIdx.x == 0) {
        float s = (wsum[0] + wsum[1] + wsum[2] + wsum[3]) * scale;
        atomicAdd(out, s);
    }
}

extern "C" void kernel_launch(void* const* d_in, const int* in_sizes, int n_in,
                              void* d_out, int out_size, void* d_ws, size_t ws_size,
                              hipStream_t stream) {
    const float* input   = (const float*)d_in[0];
    const float* targets = (const float*)d_in[1];
    float* out = (float*)d_out;

    const int B = in_sizes[0] / (2 * N_PTS);
    const float scale = 1.0f / ((float)B * (float)(2 * N_PTS));

    // d_out is poisoned 0xAA before every call — zero it (graph-capturable).
    hipMemsetAsync(d_out, 0, sizeof(float) * (size_t)out_size, stream);

    const int blocks = (B + 3) / 4;  // 4 waves (= 4 batches) per 256-thread block
    greedy_match_kernel<<<blocks, 256, 0, stream>>>(input, targets, out, B, scale);
}